// Round 1
// baseline (450.490 us; speedup 1.0000x reference)
//
#include <hip/hip_runtime.h>
#include <hip/hip_bf16.h>

// FeatureExtractionModel on MI355X.
// Stage 1: fused embedding (combined ESM+emb weights) via bf16 MFMA -> LN -> rec_edge/pep (bf16)
// Stage 2: 4x GraphAttention layers, per-wave MFMA q/key/val + shuffle softmax over 10 neighbors
// Stage 3: pooling in fp32 (LN + MLP + double softmax over sequence + projection)

typedef __attribute__((ext_vector_type(8))) short bf16x8;
typedef __attribute__((ext_vector_type(4))) float f32x4;

#define MFMA(a, b, c) __builtin_amdgcn_mfma_f32_16x16x32_bf16((a), (b), (c), 0, 0, 0)

// WB pack buffer offsets (in bf16 elements). Fragment layout per region:
//   idx = ((kc*4 + n)*64 + lane)*8 + j ; k = kc*32 + (lane>>4)*8 + j ; col = n*16 + (lane&15)
#define WB_REC_OFF   0        // 41 kc (40 ESM + 1 head, zero-padded past 21)
#define WB_PEP_OFF   83968    // 41 kc (40 ESM + 1 head, zero-padded past 27)
#define WB_EDGE_OFF  167936   // 1 kc
#define WB_P_OFF     169984   // 4 layers x 2 kc
#define WB_R_OFF     186368   // 4 layers x 4 kc
#define WB_V_OFF     219136   // 4 layers x 4 kc
#define WB_TOTAL     251904

__device__ __forceinline__ unsigned short f2bf(float x) {
  __hip_bfloat16 h = __float2bfloat16(x);
  return __builtin_bit_cast(unsigned short, h);
}
__device__ __forceinline__ float bf2f(unsigned short u) {
  unsigned int t = ((unsigned int)u) << 16;
  return __builtin_bit_cast(float, t);
}
__device__ __forceinline__ bf16x8 loadB(const unsigned short* base, int kc, int n, int lane) {
  return *(const bf16x8*)(base + ((size_t)(kc * 4 + n) * 64 + lane) * 8);
}

// ---------------- weight combine: W_comb = W_emb[:,esm:] @ W_esm  (fp32) ----------------
__global__ __launch_bounds__(256) void k_comb(
    const float* __restrict__ Wre, const float* __restrict__ Wresm,
    const float* __restrict__ Wpe, const float* __restrict__ Wpesm,
    float* __restrict__ comb_rec, float* __restrict__ comb_pep) {
  int idx = blockIdx.x * 256 + threadIdx.x;  // 163840 total
  if (idx < 81920) {
    int o = idx / 1280, k = idx - o * 1280;
    float s = 0.f;
#pragma unroll 8
    for (int e = 0; e < 64; ++e) s += Wre[o * 85 + 21 + e] * Wresm[e * 1280 + k];
    comb_rec[idx] = s;
  } else {
    int u = idx - 81920;
    int o = u / 1280, k = u - o * 1280;
    float s = 0.f;
#pragma unroll 8
    for (int e = 0; e < 64; ++e) s += Wpe[o * 91 + 27 + e] * Wpesm[e * 1280 + k];
    comb_pep[u] = s;
  }
}

// ---------------- pack all B-operand fragments to bf16 ----------------
__global__ __launch_bounds__(256) void k_pack(
    const float* __restrict__ comb_rec, const float* __restrict__ comb_pep,
    const float* __restrict__ Wre, const float* __restrict__ Wpe,
    const float* __restrict__ Wedge, const float* __restrict__ Wp,
    const float* __restrict__ Wr, const float* __restrict__ Wv,
    unsigned short* __restrict__ WB) {
  int t = blockIdx.x * 256 + threadIdx.x;
  if (t >= WB_TOTAL) return;
  float v = 0.f;
  if (t < WB_EDGE_OFF) {  // rec / pep combined + head
    bool isPep = (t >= WB_PEP_OFF);
    int u = isPep ? (t - WB_PEP_OFF) : t;
    int j = u & 7, lane = (u >> 3) & 63, n = (u >> 9) & 3, kc = u >> 11;
    int k = kc * 32 + ((lane >> 4) << 3) + j;
    int col = n * 16 + (lane & 15);
    if (kc < 40) {
      v = (isPep ? comb_pep : comb_rec)[col * 1280 + k];
    } else {
      int kl = k - 1280;
      if (isPep) v = (kl < 27) ? Wpe[col * 91 + kl] : 0.f;
      else       v = (kl < 21) ? Wre[col * 85 + kl] : 0.f;
    }
  } else if (t < WB_P_OFF) {  // edge
    int u = t - WB_EDGE_OFF;
    int j = u & 7, lane = (u >> 3) & 63, n = (u >> 9) & 3;
    int k = ((lane >> 4) << 3) + j;
    int col = n * 16 + (lane & 15);
    v = Wedge[col * 32 + k];
  } else if (t < WB_R_OFF) {  // ga_Wp [4][64][64]
    int u = t - WB_P_OFF;
    int l = u >> 12, w = u & 4095;
    int j = w & 7, lane = (w >> 3) & 63, n = (w >> 9) & 3, kc = w >> 11;
    int k = kc * 32 + ((lane >> 4) << 3) + j;
    int col = n * 16 + (lane & 15);
    v = Wp[l * 4096 + col * 64 + k];
  } else if (t < WB_V_OFF) {  // ga_Wr [4][64][128]
    int u = t - WB_R_OFF;
    int l = u >> 13, w = u & 8191;
    int j = w & 7, lane = (w >> 3) & 63, n = (w >> 9) & 3, kc = w >> 11;
    int k = kc * 32 + ((lane >> 4) << 3) + j;
    int col = n * 16 + (lane & 15);
    v = Wr[l * 8192 + col * 128 + k];
  } else {  // ga_Wv [4][64][128]
    int u = t - WB_V_OFF;
    int l = u >> 13, w = u & 8191;
    int j = w & 7, lane = (w >> 3) & 63, n = (w >> 9) & 3, kc = w >> 11;
    int k = kc * 32 + ((lane >> 4) << 3) + j;
    int col = n * 16 + (lane & 15);
    v = Wv[l * 8192 + col * 128 + k];
  }
  WB[t] = f2bf(v);
}

// ---------------- stage 1: rec embedding + edge + LN -> rec_edge [81920][128] bf16 ----------------
__global__ __launch_bounds__(128) void k_rec(
    const float* __restrict__ rec_feat, const float* __restrict__ edge_feat,
    const unsigned short* __restrict__ WB,
    const float* __restrict__ ln_g, const float* __restrict__ ln_b,
    unsigned short* __restrict__ rec_edge) {
  const int lane = threadIdx.x & 63;
  const int wid = threadIdx.x >> 6;
  const int quad = lane >> 4, lr = lane & 15;
  const int koff = quad * 8;
  const int wrow = blockIdx.x * 64 + wid * 32;  // wave handles 2 tiles x 16 rows

  const f32x4 fz = {0.f, 0.f, 0.f, 0.f};
  f32x4 acc[2][4], acce[2][4];
#pragma unroll
  for (int t = 0; t < 2; ++t)
#pragma unroll
    for (int n = 0; n < 4; ++n) { acc[t][n] = fz; acce[t][n] = fz; }

  const float* rp[2] = {rec_feat + (size_t)(wrow + lr) * 1322,
                        rec_feat + (size_t)(wrow + 16 + lr) * 1322};

  for (int kc = 0; kc < 41; ++kc) {
    bf16x8 bfr[4];
    const unsigned short* wb = WB + WB_REC_OFF + kc * 2048 + lane * 8;
#pragma unroll
    for (int n = 0; n < 4; ++n) bfr[n] = *(const bf16x8*)(wb + n * 512);
    const int base = (kc < 40) ? (42 + kc * 32 + koff) : koff;  // head chunk: B zero-padded past col 20
#pragma unroll
    for (int t = 0; t < 2; ++t) {
      const float* p = rp[t] + base;
      float x[8];
#pragma unroll
      for (int m = 0; m < 4; ++m) {
        const float2 f = *(const float2*)(p + 2 * m);
        x[2 * m] = f.x; x[2 * m + 1] = f.y;
      }
      bf16x8 a;
#pragma unroll
      for (int j = 0; j < 8; ++j) a[j] = (short)f2bf(x[j]);
#pragma unroll
      for (int n = 0; n < 4; ++n) acc[t][n] = MFMA(a, bfr[n], acc[t][n]);
    }
  }
  {  // edge embedding (K=32, one chunk)
    bf16x8 bfe[4];
    const unsigned short* wb = WB + WB_EDGE_OFF + lane * 8;
#pragma unroll
    for (int n = 0; n < 4; ++n) bfe[n] = *(const bf16x8*)(wb + n * 512);
#pragma unroll
    for (int t = 0; t < 2; ++t) {
      const float* p = edge_feat + (size_t)(wrow + t * 16 + lr) * 32 + koff;
      const float4 f0 = *(const float4*)(p);
      const float4 f1 = *(const float4*)(p + 4);
      float x[8] = {f0.x, f0.y, f0.z, f0.w, f1.x, f1.y, f1.z, f1.w};
      bf16x8 a;
#pragma unroll
      for (int j = 0; j < 8; ++j) a[j] = (short)f2bf(x[j]);
#pragma unroll
      for (int n = 0; n < 4; ++n) acce[t][n] = MFMA(a, bfe[n], acce[t][n]);
    }
  }
  float gv[4], bvl[4];
#pragma unroll
  for (int n = 0; n < 4; ++n) { gv[n] = ln_g[lr + 16 * n]; bvl[n] = ln_b[lr + 16 * n]; }

#pragma unroll
  for (int t = 0; t < 2; ++t) {
    float s[4], sq[4];
#pragma unroll
    for (int i = 0; i < 4; ++i) {
      s[i] = acc[t][0][i] + acc[t][1][i] + acc[t][2][i] + acc[t][3][i];
      sq[i] = acc[t][0][i] * acc[t][0][i] + acc[t][1][i] * acc[t][1][i] +
              acc[t][2][i] * acc[t][2][i] + acc[t][3][i] * acc[t][3][i];
    }
#pragma unroll
    for (int msk = 1; msk < 16; msk <<= 1) {
#pragma unroll
      for (int i = 0; i < 4; ++i) {
        s[i] += __shfl_xor(s[i], msk);
        sq[i] += __shfl_xor(sq[i], msk);
      }
    }
#pragma unroll
    for (int i = 0; i < 4; ++i) {
      const float mean = s[i] * (1.f / 64.f);
      const float var = sq[i] * (1.f / 64.f) - mean * mean;
      const float rstd = rsqrtf(var + 1e-5f);
      const int row = wrow + t * 16 + quad * 4 + i;
      unsigned short* dst = rec_edge + (size_t)row * 128;
#pragma unroll
      for (int n = 0; n < 4; ++n) {
        dst[lr + 16 * n] = f2bf((acc[t][n][i] - mean) * rstd * gv[n] + bvl[n]);
        dst[64 + lr + 16 * n] = f2bf(acce[t][n][i]);
      }
    }
  }
}

// ---------------- stage 1: pep embedding + LN -> pep [8192][64] bf16 ----------------
__global__ __launch_bounds__(128) void k_pep(
    const float* __restrict__ pep_feat, const unsigned short* __restrict__ WB,
    const float* __restrict__ ln_g, const float* __restrict__ ln_b,
    unsigned short* __restrict__ pep) {
  const int lane = threadIdx.x & 63;
  const int wid = threadIdx.x >> 6;
  const int quad = lane >> 4, lr = lane & 15;
  const int koff = quad * 8;
  const int row0 = blockIdx.x * 32 + wid * 16;

  const f32x4 fz = {0.f, 0.f, 0.f, 0.f};
  f32x4 acc[4] = {fz, fz, fz, fz};
  const float* rp = pep_feat + (size_t)(row0 + lr) * 1307;

  for (int kc = 0; kc < 41; ++kc) {
    bf16x8 bfr[4];
    const unsigned short* wb = WB + WB_PEP_OFF + kc * 2048 + lane * 8;
#pragma unroll
    for (int n = 0; n < 4; ++n) bfr[n] = *(const bf16x8*)(wb + n * 512);
    const int base = (kc < 40) ? (27 + kc * 32 + koff) : koff;
    const float* p = rp + base;
    float x[8];
#pragma unroll
    for (int j = 0; j < 8; ++j) x[j] = p[j];
    bf16x8 a;
#pragma unroll
    for (int j = 0; j < 8; ++j) a[j] = (short)f2bf(x[j]);
#pragma unroll
    for (int n = 0; n < 4; ++n) acc[n] = MFMA(a, bfr[n], acc[n]);
  }
  float gv[4], bvl[4];
#pragma unroll
  for (int n = 0; n < 4; ++n) { gv[n] = ln_g[lr + 16 * n]; bvl[n] = ln_b[lr + 16 * n]; }

  float s[4], sq[4];
#pragma unroll
  for (int i = 0; i < 4; ++i) {
    s[i] = acc[0][i] + acc[1][i] + acc[2][i] + acc[3][i];
    sq[i] = acc[0][i] * acc[0][i] + acc[1][i] * acc[1][i] +
            acc[2][i] * acc[2][i] + acc[3][i] * acc[3][i];
  }
#pragma unroll
  for (int msk = 1; msk < 16; msk <<= 1) {
#pragma unroll
    for (int i = 0; i < 4; ++i) {
      s[i] += __shfl_xor(s[i], msk);
      sq[i] += __shfl_xor(sq[i], msk);
    }
  }
#pragma unroll
  for (int i = 0; i < 4; ++i) {
    const float mean = s[i] * (1.f / 64.f);
    const float var = sq[i] * (1.f / 64.f) - mean * mean;
    const float rstd = rsqrtf(var + 1e-5f);
    const int row = row0 + quad * 4 + i;
    unsigned short* dst = pep + (size_t)row * 64;
#pragma unroll
    for (int n = 0; n < 4; ++n)
      dst[lr + 16 * n] = f2bf((acc[n][i] - mean) * rstd * gv[n] + bvl[n]);
  }
}

// ---------------- stage 2: one GraphAttention layer (in-place pep update) ----------------
__global__ __launch_bounds__(64) void k_ga(
    const unsigned short* __restrict__ rec_edge, unsigned short* __restrict__ pep,
    const unsigned short* __restrict__ WB,
    const float* __restrict__ bp, const float* __restrict__ br, const float* __restrict__ bv,
    const int layer) {
  __shared__ float qs[16][68];
  const int lane = threadIdx.x & 63;
  const int quad = lane >> 4, lr = lane & 15;
  const int pbase = blockIdx.x * 16;

  const unsigned short* WBp = WB + WB_P_OFF + layer * 4096;
  const unsigned short* WBr = WB + WB_R_OFF + layer * 8192;
  const unsigned short* WBv = WB + WB_V_OFF + layer * 8192;

  float bpv[4], brv[4], bvv[4];
#pragma unroll
  for (int n = 0; n < 4; ++n) {
    bpv[n] = bp[lr + 16 * n];
    brv[n] = br[lr + 16 * n];
    bvv[n] = bv[lr + 16 * n];
  }
  const f32x4 fz = {0.f, 0.f, 0.f, 0.f};
  const bf16x8 bz = {0, 0, 0, 0, 0, 0, 0, 0};

  {  // q = pep @ Wp^T + bp, into LDS
    const unsigned short* prow = pep + (size_t)(pbase + lr) * 64 + quad * 8;
    f32x4 qacc[4] = {fz, fz, fz, fz};
#pragma unroll
    for (int kc = 0; kc < 2; ++kc) {
      bf16x8 a = *(const bf16x8*)(prow + kc * 32);
#pragma unroll
      for (int n = 0; n < 4; ++n) qacc[n] = MFMA(a, loadB(WBp, kc, n, lane), qacc[n]);
    }
#pragma unroll
    for (int n = 0; n < 4; ++n)
#pragma unroll
      for (int i = 0; i < 4; ++i)
        qs[quad * 4 + i][lr + 16 * n] = qacc[n][i] + bpv[n];
  }
  // single wave per block: LDS deps handled by lgkmcnt, no barrier needed.

  auto loadA = [&](int it2, bf16x8 a4[4]) {
    if (lr < 10) {
      const unsigned short* rp2 = rec_edge + ((size_t)(pbase + it2) * 10 + lr) * 128 + quad * 8;
#pragma unroll
      for (int kc = 0; kc < 4; ++kc) a4[kc] = *(const bf16x8*)(rp2 + kc * 32);
    } else {
#pragma unroll
      for (int kc = 0; kc < 4; ++kc) a4[kc] = bz;
    }
  };

  bf16x8 av[4];
  loadA(0, av);
  for (int it = 0; it < 16; ++it) {
    bf16x8 avn[4];
    if (it < 15) loadA(it + 1, avn);
    else { avn[0] = bz; avn[1] = bz; avn[2] = bz; avn[3] = bz; }

    // key = rec_edge @ Wr^T (+ br in the dot below)
    f32x4 kacc[4] = {fz, fz, fz, fz};
#pragma unroll
    for (int kc = 0; kc < 4; ++kc)
#pragma unroll
      for (int n = 0; n < 4; ++n) kacc[n] = MFMA(av[kc], loadB(WBr, kc, n, lane), kacc[n]);

    float qv[4];
#pragma unroll
    for (int n = 0; n < 4; ++n) qv[n] = qs[it][lr + 16 * n];

    float lg[4];
#pragma unroll
    for (int i = 0; i < 4; ++i) {
      float tt = (kacc[0][i] + brv[0]) * qv[0] + (kacc[1][i] + brv[1]) * qv[1] +
                 (kacc[2][i] + brv[2]) * qv[2] + (kacc[3][i] + brv[3]) * qv[3];
      tt += __shfl_xor(tt, 1);
      tt += __shfl_xor(tt, 2);
      tt += __shfl_xor(tt, 4);
      tt += __shfl_xor(tt, 8);
      lg[i] = tt * 0.125f;
      if (quad * 4 + i >= 10) lg[i] = -1e30f;
    }
    float mx = fmaxf(fmaxf(lg[0], lg[1]), fmaxf(lg[2], lg[3]));
    mx = fmaxf(mx, __shfl_xor(mx, 16));
    mx = fmaxf(mx, __shfl_xor(mx, 32));
    float e[4], ss = 0.f;
#pragma unroll
    for (int i = 0; i < 4; ++i) {
      e[i] = (quad * 4 + i < 10) ? __expf(lg[i] - mx) : 0.f;
      ss += e[i];
    }
    ss += __shfl_xor(ss, 16);
    ss += __shfl_xor(ss, 32);
    const float inv = 1.f / ss;

    // val = rec_edge @ Wv^T (+ bv)
    f32x4 vacc[4] = {fz, fz, fz, fz};
#pragma unroll
    for (int kc = 0; kc < 4; ++kc)
#pragma unroll
      for (int n = 0; n < 4; ++n) vacc[n] = MFMA(av[kc], loadB(WBv, kc, n, lane), vacc[n]);

#pragma unroll
    for (int n = 0; n < 4; ++n) {
      float tt = e[0] * (vacc[n][0] + bvv[n]) + e[1] * (vacc[n][1] + bvv[n]) +
                 e[2] * (vacc[n][2] + bvv[n]) + e[3] * (vacc[n][3] + bvv[n]);
      tt += __shfl_xor(tt, 16);
      tt += __shfl_xor(tt, 32);
      const float o = tt * inv + qs[it][lr + 16 * n];
      if (lane < 16) pep[(size_t)(pbase + it) * 64 + lr + 16 * n] = f2bf(o);
    }
#pragma unroll
    for (int kc = 0; kc < 4; ++kc) av[kc] = avn[kc];
  }
}

// ---------------- stage 3a: d = LN(pep); MLP -> logitsT [b*16+h][2048], dbuf [8192][64] ----------------
__global__ __launch_bounds__(64) void k_pool1(
    const unsigned short* __restrict__ pep, const float* __restrict__ g,
    const float* __restrict__ b, const float* __restrict__ W0,
    const float* __restrict__ W1, const float* __restrict__ W2,
    float* __restrict__ dbuf, float* __restrict__ logitsT) {
  const int row = blockIdx.x * 64 + threadIdx.x;  // 8192
  float d[64];
  float s = 0.f, sq = 0.f;
  const uint4* pr4 = (const uint4*)(pep + (size_t)row * 64);
#pragma unroll
  for (int m = 0; m < 8; ++m) {
    uint4 q = pr4[m];
    unsigned int w[4] = {q.x, q.y, q.z, q.w};
#pragma unroll
    for (int t2 = 0; t2 < 4; ++t2) {
      float lo = bf2f((unsigned short)(w[t2] & 0xffffu));
      float hi = bf2f((unsigned short)(w[t2] >> 16));
      d[m * 8 + t2 * 2] = lo;
      d[m * 8 + t2 * 2 + 1] = hi;
      s += lo + hi;
      sq += lo * lo + hi * hi;
    }
  }
  const float mean = s * (1.f / 64.f);
  const float var = sq * (1.f / 64.f) - mean * mean;
  const float rstd = rsqrtf(var + 1e-5f);
  float* dr = dbuf + (size_t)row * 64;
#pragma unroll
  for (int k = 0; k < 64; ++k) d[k] = (d[k] - mean) * rstd * g[k] + b[k];
#pragma unroll
  for (int m = 0; m < 16; ++m) {
    float4 v = {d[4 * m], d[4 * m + 1], d[4 * m + 2], d[4 * m + 3]};
    *(float4*)(dr + 4 * m) = v;
  }
  float h1[32];
#pragma unroll
  for (int j = 0; j < 32; ++j) h1[j] = 0.f;
  for (int o = 0; o < 64; ++o) {
    float t = 0.f;
#pragma unroll
    for (int k = 0; k < 64; ++k) t += d[k] * W0[o * 64 + k];
    t = tanhf(t);
#pragma unroll
    for (int j = 0; j < 32; ++j) h1[j] += t * W1[j * 64 + o];
  }
  float lg[16];
#pragma unroll
  for (int h = 0; h < 16; ++h) lg[h] = 0.f;
  for (int j = 0; j < 32; ++j) {
    float t = tanhf(h1[j]);
#pragma unroll
    for (int h = 0; h < 16; ++h) lg[h] += t * W2[h * 32 + j];
  }
  const int bb = row >> 11, sx = row & 2047;
#pragma unroll
  for (int h = 0; h < 16; ++h) logitsT[((size_t)bb * 16 + h) * 2048 + sx] = lg[h];
}

// ---------------- stage 3b: double softmax over s + attended ----------------
__global__ __launch_bounds__(256) void k_pool2(
    const float* __restrict__ logitsT, const float* __restrict__ dbuf,
    float* __restrict__ attended) {
  __shared__ float sh[2048];
  __shared__ float red[8];
  __shared__ float accs[4][64];
  const int bh = blockIdx.x, b = bh >> 4;
  const int tid = threadIdx.x, lane = tid & 63, wid = tid >> 6;
  const float* lrow = logitsT + (size_t)bh * 2048;

  float m = -1e30f;
  for (int sx = tid; sx < 2048; sx += 256) {
    float v = lrow[sx];
    sh[sx] = v;
    m = fmaxf(m, v);
  }
#pragma unroll
  for (int msk = 1; msk < 64; msk <<= 1) m = fmaxf(m, __shfl_xor(m, msk));
  if (lane == 0) red[wid] = m;
  __syncthreads();
  m = fmaxf(fmaxf(red[0], red[1]), fmaxf(red[2], red[3]));

  float s1 = 0.f;
  for (int sx = tid; sx < 2048; sx += 256) {
    float e = __expf(sh[sx] - m);
    sh[sx] = e;
    s1 += e;
  }
#pragma unroll
  for (int msk = 1; msk < 64; msk <<= 1) s1 += __shfl_xor(s1, msk);
  __syncthreads();
  if (lane == 0) red[4 + wid] = s1;
  __syncthreads();
  s1 = red[4] + red[5] + red[6] + red[7];
  const float invS1 = 1.f / s1;  // max(a1) = 1/S1 exactly (max e == 1)

  float s2 = 0.f;
  for (int sx = tid; sx < 2048; sx += 256) {
    float e2 = __expf((sh[sx] - 1.f) * invS1);
    sh[sx] = e2;
    s2 += e2;
  }
#pragma unroll
  for (int msk = 1; msk < 64; msk <<= 1) s2 += __shfl_xor(s2, msk);
  __syncthreads();
  if (lane == 0) red[wid] = s2;
  __syncthreads();
  s2 = red[0] + red[1] + red[2] + red[3];
  const float invS2 = 1.f / s2;

  float acc = 0.f;
  for (int sx = wid; sx < 2048; sx += 4)
    acc += sh[sx] * dbuf[((size_t)b * 2048 + sx) * 64 + lane];
  accs[wid][lane] = acc * invS2;
  __syncthreads();
  if (tid < 64)
    attended[(size_t)bh * 64 + tid] =
        accs[0][tid] + accs[1][tid] + accs[2][tid] + accs[3][tid];
}

// ---------------- stage 3c: pooled mean over heads + final projection ----------------
__global__ __launch_bounds__(256) void k_final(
    const float* __restrict__ attended, const float* __restrict__ W,
    const float* __restrict__ bias, float* __restrict__ out) {
  __shared__ float pooled[4][64];
  const int tid = threadIdx.x;
  {
    const int b = tid >> 6, d = tid & 63;
    float s = 0.f;
#pragma unroll
    for (int h = 0; h < 16; ++h) s += attended[((size_t)b * 16 + h) * 64 + d];
    pooled[b][d] = s * (1.f / 16.f);
  }
  __syncthreads();
  if (tid < 128) {
    const int b = tid >> 5, j = tid & 31;
    float s = bias[j];
#pragma unroll
    for (int d2 = 0; d2 < 64; ++d2) s += pooled[b][d2] * W[j * 64 + d2];
    out[b * 32 + j] = s;
  }
}

extern "C" void kernel_launch(void* const* d_in, const int* in_sizes, int n_in,
                              void* d_out, int out_size, void* d_ws, size_t ws_size,
                              hipStream_t stream) {
  const float* pep_feat = (const float*)d_in[0];
  const float* rec_feat = (const float*)d_in[1];
  const float* edge_feat = (const float*)d_in[2];
  const float* W_rec_esm = (const float*)d_in[3];
  const float* W_pep_esm = (const float*)d_in[4];
  const float* W_pep_emb = (const float*)d_in[5];
  const float* W_rec_emb = (const float*)d_in[6];
  const float* W_edge_emb = (const float*)d_in[7];
  const float* pep_ln_g = (const float*)d_in[8];
  const float* pep_ln_b = (const float*)d_in[9];
  const float* rec_ln_g = (const float*)d_in[10];
  const float* rec_ln_b = (const float*)d_in[11];
  const float* ga_Wp = (const float*)d_in[12];
  const float* ga_bp = (const float*)d_in[13];
  const float* ga_Wr = (const float*)d_in[14];
  const float* ga_br = (const float*)d_in[15];
  const float* ga_Wv = (const float*)d_in[16];
  const float* ga_bv = (const float*)d_in[17];
  const float* pool_ln_g = (const float*)d_in[18];
  const float* pool_ln_b = (const float*)d_in[19];
  const float* pool_W0 = (const float*)d_in[20];
  const float* pool_W1 = (const float*)d_in[21];
  const float* pool_W2 = (const float*)d_in[22];
  const float* mlp_W = (const float*)d_in[23];
  const float* mlp_b = (const float*)d_in[24];
  float* out = (float*)d_out;

  char* ws = (char*)d_ws;
  float* comb_rec = (float*)(ws + 0);                           // 327680 B
  float* comb_pep = (float*)(ws + 327680);                      // 327680 B
  unsigned short* WB = (unsigned short*)(ws + 655360);          // 503808 B
  unsigned short* rec_edge = (unsigned short*)(ws + 1159168);   // 20971520 B
  unsigned short* pep = (unsigned short*)(ws + 22130688);       // 1048576 B
  float* dbuf = (float*)(ws + 23179264);                        // 2097152 B
  float* logitsT = (float*)(ws + 25276416);                     // 524288 B
  float* attended = (float*)(ws + 25800704);                    // 16384 B
  (void)ws_size; (void)in_sizes; (void)n_in; (void)out_size;

  k_comb<<<640, 256, 0, stream>>>(W_rec_emb, W_rec_esm, W_pep_emb, W_pep_esm,
                                  comb_rec, comb_pep);
  k_pack<<<984, 256, 0, stream>>>(comb_rec, comb_pep, W_rec_emb, W_pep_emb,
                                  W_edge_emb, ga_Wp, ga_Wr, ga_Wv, WB);
  k_rec<<<1280, 128, 0, stream>>>(rec_feat, edge_feat, WB, rec_ln_g, rec_ln_b,
                                  rec_edge);
  k_pep<<<256, 128, 0, stream>>>(pep_feat, WB, pep_ln_g, pep_ln_b, pep);
  for (int l = 0; l < 4; ++l)
    k_ga<<<512, 64, 0, stream>>>(rec_edge, pep, WB, ga_bp + l * 64,
                                 ga_br + l * 64, ga_bv + l * 64, l);
  k_pool1<<<128, 64, 0, stream>>>(pep, pool_ln_g, pool_ln_b, pool_W0, pool_W1,
                                  pool_W2, dbuf, logitsT);
  k_pool2<<<64, 256, 0, stream>>>(logitsT, dbuf, attended);
  k_final<<<1, 256, 0, stream>>>(attended, mlp_W, mlp_b, out);
}

// Round 2
// 328.954 us; speedup vs baseline: 1.3695x; 1.3695x over previous
//
#include <hip/hip_runtime.h>
#include <hip/hip_bf16.h>

// FeatureExtractionModel on MI355X — round 2.
// k_pack : all MFMA B-fragments (with inline ESM-weight combine)
// k_rec  : rec+edge embedding, LDS-staged coalesced loads -> LN -> rec_edge bf16
// k_fused: pep embedding + 4 GraphAttention layers (z-reformulation) + pool MLP
// k_pool2/k_final: double softmax pooling + projection (unchanged, fp32)

typedef __attribute__((ext_vector_type(8))) short bf16x8;
typedef __attribute__((ext_vector_type(4))) float f32x4;
typedef __attribute__((ext_vector_type(4))) unsigned int u32x4;

#define MFMA(a, b, c) __builtin_amdgcn_mfma_f32_16x16x32_bf16((a), (b), (c), 0, 0, 0)

// WB pack buffer offsets (bf16 elements). Fragment layout per chunk:
//   idx = (chunk*64 + lane)*8 + j
#define WB_REC_OFF   0        // 41 kc x 4 n  (40 ESM-combined + 1 head)
#define WB_PEP_OFF   83968    // 41 kc x 4 n
#define WB_EDGE_OFF  167936   // 1 kc x 4 n
#define WB_P_OFF     169984   // 4 layers x (2 kc x 4 n)   B[o][d]=Wp[d][o]
#define WB_R_OFF     186368   // 4 layers x (2 kc x 8 n)   B[o][k]=Wr[o][k]  (z orientation)
#define WB_V_OFF     219136   // 4 layers x (4 kc x 4 n)   B[k][d]=Wv[d][k]
#define WB_W0_OFF    251904   // 2 kc x 4 n                B[k][o]=W0[o][k]
#define WB_W1_OFF    256000   // 2 kc x 2 n                B[o][o2]=W1[o2][o]
#define WB_W2_OFF    258048   // 1 chunk                   B[j][h]=W2[h][j]
#define WB_TOTAL     258560

__device__ __forceinline__ unsigned short f2bf(float x) {
  __hip_bfloat16 h = __float2bfloat16(x);
  return __builtin_bit_cast(unsigned short, h);
}
__device__ __forceinline__ float bf2f(unsigned short u) {
  unsigned int t = ((unsigned int)u) << 16;
  return __builtin_bit_cast(float, t);
}
__device__ __forceinline__ bf16x8 loadBc(const unsigned short* base, int chunk, int lane) {
  return *(const bf16x8*)(base + ((size_t)chunk * 64 + lane) * 8);
}
__device__ __forceinline__ float tanhf_fast(float x) {
  float e = __expf(2.f * x);
  return 1.f - 2.f / (e + 1.f);
}

// ---------------- pack all B-operand fragments to bf16 (inline ESM combine) ----------------
__global__ __launch_bounds__(256) void k_pack(
    const float* __restrict__ Wresm, const float* __restrict__ Wpesm,
    const float* __restrict__ Wre, const float* __restrict__ Wpe,
    const float* __restrict__ Wedge, const float* __restrict__ Wp,
    const float* __restrict__ Wr, const float* __restrict__ Wv,
    const float* __restrict__ W0, const float* __restrict__ W1,
    const float* __restrict__ W2, unsigned short* __restrict__ WB) {
  const int t = blockIdx.x * 256 + threadIdx.x;
  if (t >= WB_TOTAL) return;
  float v = 0.f;
  if (t < WB_EDGE_OFF) {  // rec / pep: combined ESM + head
    bool isPep = (t >= WB_PEP_OFF);
    int u = isPep ? (t - WB_PEP_OFF) : t;
    int j = u & 7, lane = (u >> 3) & 63, n = (u >> 9) & 3, kc = u >> 11;
    int k = kc * 32 + ((lane >> 4) << 3) + j;
    int col = n * 16 + (lane & 15);
    if (kc < 40) {
      // W_comb[col][k] = sum_e W_emb[col][head+e] * W_esm[e][k]
      const float* wemb = isPep ? (Wpe + col * 91 + 27) : (Wre + col * 85 + 21);
      const float* wesm = isPep ? Wpesm : Wresm;
      float s = 0.f;
#pragma unroll 8
      for (int e = 0; e < 64; ++e) s += wemb[e] * wesm[e * 1280 + k];
      v = s;
    } else {
      int kl = k - 1280;
      if (isPep) v = (kl < 27) ? Wpe[col * 91 + kl] : 0.f;
      else       v = (kl < 21) ? Wre[col * 85 + kl] : 0.f;
    }
  } else if (t < WB_P_OFF) {  // edge
    int u = t - WB_EDGE_OFF;
    int j = u & 7, lane = (u >> 3) & 63, n = (u >> 9) & 3;
    v = Wedge[(n * 16 + (lane & 15)) * 32 + ((lane >> 4) << 3) + j];
  } else if (t < WB_R_OFF) {  // ga_Wp: B[o][d] = Wp[d][o]
    int u = t - WB_P_OFF;
    int l = u >> 12, w = u & 4095;
    int j = w & 7, lane = (w >> 3) & 63, n = (w >> 9) & 3, kc = w >> 11;
    int o = kc * 32 + ((lane >> 4) << 3) + j;
    int d = n * 16 + (lane & 15);
    v = Wp[l * 4096 + d * 64 + o];
  } else if (t < WB_V_OFF) {  // ga_Wr z-orientation: B[o][k] = Wr[o][k]
    int u = t - WB_R_OFF;
    int l = u >> 13, w = u & 8191;
    int j = w & 7, lane = (w >> 3) & 63, c = (w >> 9) & 15;
    int kc = c >> 3, n = c & 7;
    int o = kc * 32 + ((lane >> 4) << 3) + j;
    int k = n * 16 + (lane & 15);
    v = Wr[l * 8192 + o * 128 + k];
  } else if (t < WB_W0_OFF) {  // ga_Wv: B[k][d] = Wv[d][k]
    int u = t - WB_V_OFF;
    int l = u >> 13, w = u & 8191;
    int j = w & 7, lane = (w >> 3) & 63, n = (w >> 9) & 3, kc = w >> 11;
    int k = kc * 32 + ((lane >> 4) << 3) + j;
    int d = n * 16 + (lane & 15);
    v = Wv[l * 8192 + d * 128 + k];
  } else if (t < WB_W1_OFF) {  // pool_W0
    int u = t - WB_W0_OFF;
    int j = u & 7, lane = (u >> 3) & 63, c = u >> 9;  // c = kc*4+n
    int kc = c >> 2, n = c & 3;
    v = W0[(n * 16 + (lane & 15)) * 64 + kc * 32 + ((lane >> 4) << 3) + j];
  } else if (t < WB_W2_OFF) {  // pool_W1
    int u = t - WB_W1_OFF;
    int j = u & 7, lane = (u >> 3) & 63, c = u >> 9;  // c = kc*2+n
    int kc = c >> 1, n = c & 1;
    v = W1[(n * 16 + (lane & 15)) * 64 + kc * 32 + ((lane >> 4) << 3) + j];
  } else {  // pool_W2
    int u = t - WB_W2_OFF;
    int j = u & 7, lane = (u >> 3) & 63;
    v = W2[(lane & 15) * 32 + ((lane >> 4) << 3) + j];
  }
  WB[t] = f2bf(v);
}

// ---------------- rec embedding + edge + LN -> rec_edge [81920][128] bf16 ----------------
__global__ __launch_bounds__(256) void k_rec(
    const float* __restrict__ rec_feat, const float* __restrict__ edge_feat,
    const unsigned short* __restrict__ WB,
    const float* __restrict__ ln_g, const float* __restrict__ ln_b,
    unsigned short* __restrict__ rec_edge) {
  __shared__ float stg[2][2048];  // 2 x [64 rows x 32 cols] f32, XOR-swizzled 16B units
  const int t = threadIdx.x;
  const int lane = t & 63, w = t >> 6;
  const int quad = lane >> 4, lr = lane & 15;
  const int brow = blockIdx.x * 64;
  const int myrow = w * 16 + lr;  // block-local row for A-frags
  const int swz = myrow & 7;

  const f32x4 fz = {0.f, 0.f, 0.f, 0.f};
  f32x4 acc[4] = {fz, fz, fz, fz};
  f32x4 acce[4] = {fz, fz, fz, fz};

  float ld[8];
  auto gload = [&](int kc) {
    const int base = (kc < 40) ? (42 + kc * 32) : 0;
#pragma unroll
    for (int i = 0; i < 8; ++i) {
      int f = t + 256 * i;
      int row = f >> 5, col = f & 31;
      ld[i] = rec_feat[(size_t)(brow + row) * 1322 + base + col];
    }
  };
  auto swrite = [&](int b) {
#pragma unroll
    for (int i = 0; i < 8; ++i) {
      int f = t + 256 * i;
      int row = f >> 5, col = f & 31;
      stg[b][row * 32 + (((col >> 2) ^ (row & 7)) << 2) + (col & 3)] = ld[i];
    }
  };

  gload(0); swrite(0);
  __syncthreads();
  for (int kc = 0; kc < 41; ++kc) {
    if (kc < 40) gload(kc + 1);
    const float4 r0 = *(const float4*)(&stg[kc & 1][myrow * 32 + ((((quad << 1) | 0) ^ swz) << 2)]);
    const float4 r1 = *(const float4*)(&stg[kc & 1][myrow * 32 + ((((quad << 1) | 1) ^ swz) << 2)]);
    bf16x8 a;
#pragma unroll
    for (int j = 0; j < 4; ++j) { a[j] = (short)f2bf(r0[j]); a[4 + j] = (short)f2bf(r1[j]); }
    const unsigned short* wb = WB + WB_REC_OFF + kc * 2048;
#pragma unroll
    for (int n = 0; n < 4; ++n) acc[n] = MFMA(a, loadBc(wb, n, lane), acc[n]);
    if (kc < 40) swrite((kc + 1) & 1);
    __syncthreads();
  }
  {  // edge embedding (aligned direct loads)
    const float* p = edge_feat + (size_t)(brow + w * 16 + lr) * 32 + quad * 8;
    const float4 f0 = *(const float4*)(p);
    const float4 f1 = *(const float4*)(p + 4);
    bf16x8 a;
#pragma unroll
    for (int j = 0; j < 4; ++j) { a[j] = (short)f2bf(f0[j]); a[4 + j] = (short)f2bf(f1[j]); }
#pragma unroll
    for (int n = 0; n < 4; ++n) acce[n] = MFMA(a, loadBc(WB + WB_EDGE_OFF, n, lane), acce[n]);
  }
  float gv[4], bvl[4];
#pragma unroll
  for (int n = 0; n < 4; ++n) { gv[n] = ln_g[lr + 16 * n]; bvl[n] = ln_b[lr + 16 * n]; }

  float s[4], sq[4];
#pragma unroll
  for (int i = 0; i < 4; ++i) {
    s[i] = acc[0][i] + acc[1][i] + acc[2][i] + acc[3][i];
    sq[i] = acc[0][i] * acc[0][i] + acc[1][i] * acc[1][i] +
            acc[2][i] * acc[2][i] + acc[3][i] * acc[3][i];
  }
#pragma unroll
  for (int msk = 1; msk < 16; msk <<= 1) {
#pragma unroll
    for (int i = 0; i < 4; ++i) {
      s[i] += __shfl_xor(s[i], msk);
      sq[i] += __shfl_xor(sq[i], msk);
    }
  }
#pragma unroll
  for (int i = 0; i < 4; ++i) {
    const float mean = s[i] * (1.f / 64.f);
    const float var = sq[i] * (1.f / 64.f) - mean * mean;
    const float rstd = rsqrtf(var + 1e-5f);
    const int row = brow + w * 16 + quad * 4 + i;
    unsigned short* dst = rec_edge + (size_t)row * 128;
#pragma unroll
    for (int n = 0; n < 4; ++n) {
      dst[lr + 16 * n] = f2bf((acc[n][i] - mean) * rstd * gv[n] + bvl[n]);
      dst[64 + lr + 16 * n] = f2bf(acce[n][i]);
    }
  }
}

// ---------------- fused: pep embed + 4 GA layers + pool MLP ----------------
__global__ __launch_bounds__(64) void k_fused(
    const float* __restrict__ pep_feat, const unsigned short* __restrict__ rec_edge,
    const unsigned short* __restrict__ WB,
    const float* __restrict__ ga_bp, const float* __restrict__ ga_bv,
    const float* __restrict__ pep_ln_g, const float* __restrict__ pep_ln_b,
    const float* __restrict__ pool_g, const float* __restrict__ pool_b,
    float* __restrict__ dbuf, float* __restrict__ logitsT) {
  __shared__ unsigned short re_s[20480];  // [16 p][10 r][128] bf16, 16B units XOR-swz by p&7
  __shared__ float stg_s[1024];           // pep-embed staging (2x512) / pool d transpose
  __shared__ float z_s[16 * 132];         // z transpose, padded stride
  __shared__ unsigned short pep_s[1024];  // [16][64] bf16, swizzled
  __shared__ unsigned short q_s[1024];    // [16][64] bf16, swizzled (q / d / h0 / h1)
  __shared__ float bias_s[512];           // bp[4][64], bv[4][64]

  const int t = threadIdx.x;
  const int quad = t >> 4, lr = t & 15;
  const int swz = lr & 7;
  const int pbase = blockIdx.x * 16;
  const f32x4 fz = {0.f, 0.f, 0.f, 0.f};

  // ---- bias + rec_edge staging ----
#pragma unroll
  for (int i = 0; i < 4; ++i) {
    int f = t + 64 * i;
    bias_s[f] = ga_bp[f];
    bias_s[256 + f] = ga_bv[f];
  }
  {
    const uint4* src = (const uint4*)(rec_edge + (size_t)pbase * 1280);
    for (int i = 0; i < 40; ++i) {
      int g = t + 64 * i;
      uint4 v = src[g];
      int p = g / 160, rem = g - p * 160;
      int r = rem >> 4, u = rem & 15;
      *(uint4*)(re_s + p * 1280 + r * 128 + ((u ^ (p & 7)) << 3)) = v;
    }
  }

  auto bwrite = [&](unsigned short* buf, int p, int col, unsigned short val) {
    buf[p * 64 + ((((col >> 3)) ^ (p & 7)) << 3) + (col & 7)] = val;
  };
  auto bfrag = [&](const unsigned short* buf, int kc) -> bf16x8 {
    return *(const bf16x8*)(buf + lr * 64 + ((((kc << 2) + quad) ^ swz) << 3));
  };

  // ---- pep embedding (41 kc staged) ----
  {
    f32x4 acc[4] = {fz, fz, fz, fz};
    float ld[8];
    auto gload = [&](int kc) {
      const int base = (kc < 40) ? (27 + kc * 32) : 0;
#pragma unroll
      for (int i = 0; i < 8; ++i) {
        int f = t + 64 * i;
        int row = f >> 5, col = f & 31;
        ld[i] = pep_feat[(size_t)(pbase + row) * 1307 + base + col];
      }
    };
    auto swrite = [&](int b) {
#pragma unroll
      for (int i = 0; i < 8; ++i) {
        int f = t + 64 * i;
        int row = f >> 5, col = f & 31;
        stg_s[b * 512 + row * 32 + (((col >> 2) ^ (row & 7)) << 2) + (col & 3)] = ld[i];
      }
    };
    gload(0); swrite(0);
    for (int kc = 0; kc < 41; ++kc) {
      if (kc < 40) gload(kc + 1);
      const float4 r0 = *(const float4*)(&stg_s[(kc & 1) * 512 + lr * 32 + ((((quad << 1) | 0) ^ swz) << 2)]);
      const float4 r1 = *(const float4*)(&stg_s[(kc & 1) * 512 + lr * 32 + ((((quad << 1) | 1) ^ swz) << 2)]);
      bf16x8 a;
#pragma unroll
      for (int j = 0; j < 4; ++j) { a[j] = (short)f2bf(r0[j]); a[4 + j] = (short)f2bf(r1[j]); }
      const unsigned short* wb = WB + WB_PEP_OFF + kc * 2048;
#pragma unroll
      for (int n = 0; n < 4; ++n) acc[n] = MFMA(a, loadBc(wb, n, t), acc[n]);
      if (kc < 40) swrite((kc + 1) & 1);
    }
    // LN
    float s[4], sq[4];
#pragma unroll
    for (int i = 0; i < 4; ++i) {
      s[i] = acc[0][i] + acc[1][i] + acc[2][i] + acc[3][i];
      sq[i] = acc[0][i] * acc[0][i] + acc[1][i] * acc[1][i] +
              acc[2][i] * acc[2][i] + acc[3][i] * acc[3][i];
    }
#pragma unroll
    for (int msk = 1; msk < 16; msk <<= 1) {
#pragma unroll
      for (int i = 0; i < 4; ++i) {
        s[i] += __shfl_xor(s[i], msk);
        sq[i] += __shfl_xor(sq[i], msk);
      }
    }
    float gv[4], bvl[4];
#pragma unroll
    for (int n = 0; n < 4; ++n) { gv[n] = pep_ln_g[lr + 16 * n]; bvl[n] = pep_ln_b[lr + 16 * n]; }
#pragma unroll
    for (int i = 0; i < 4; ++i) {
      const float mean = s[i] * (1.f / 64.f);
      const float var = sq[i] * (1.f / 64.f) - mean * mean;
      const float rstd = rsqrtf(var + 1e-5f);
#pragma unroll
      for (int n = 0; n < 4; ++n)
        bwrite(pep_s, quad * 4 + i, lr + 16 * n, f2bf((acc[n][i] - mean) * rstd * gv[n] + bvl[n]));
    }
  }

  // ---- 4 GraphAttention layers ----
  f32x4 pcur[4];  // final pep (fp32, C-layout) for pooling
  for (int l = 0; l < 4; ++l) {
    const unsigned short* WBp = WB + WB_P_OFF + l * 4096;
    const unsigned short* WBr = WB + WB_R_OFF + l * 8192;
    const unsigned short* WBv = WB + WB_V_OFF + l * 8192;
    // q = pep @ Wp^T + bp
    f32x4 qa[4] = {fz, fz, fz, fz};
#pragma unroll
    for (int kc = 0; kc < 2; ++kc) {
      bf16x8 a = bfrag(pep_s, kc);
#pragma unroll
      for (int n = 0; n < 4; ++n) qa[n] = MFMA(a, loadBc(WBp, kc * 4 + n, t), qa[n]);
    }
#pragma unroll
    for (int n = 0; n < 4; ++n) {
      const float bpv = bias_s[l * 64 + lr + 16 * n];
#pragma unroll
      for (int i = 0; i < 4; ++i) qa[n][i] += bpv;
    }
    // q -> bf16 frags
#pragma unroll
    for (int n = 0; n < 4; ++n)
#pragma unroll
      for (int i = 0; i < 4; ++i)
        bwrite(q_s, quad * 4 + i, lr + 16 * n, f2bf(qa[n][i]));
    const bf16x8 aq0 = bfrag(q_s, 0), aq1 = bfrag(q_s, 1);
    // z = Wr^T q   [16 p x 128 k]
    f32x4 za[8] = {fz, fz, fz, fz, fz, fz, fz, fz};
#pragma unroll
    for (int n = 0; n < 8; ++n) za[n] = MFMA(aq0, loadBc(WBr, n, t), za[n]);
#pragma unroll
    for (int n = 0; n < 8; ++n) za[n] = MFMA(aq1, loadBc(WBr, 8 + n, t), za[n]);
    // transpose z via LDS -> per-lane A-layout (fp32)
#pragma unroll
    for (int n = 0; n < 8; ++n)
#pragma unroll
      for (int i = 0; i < 4; ++i)
        z_s[(quad * 4 + i) * 132 + lr + 16 * n] = za[n][i];
    float4 zr[8];
#pragma unroll
    for (int c = 0; c < 8; ++c)
      zr[c] = *(const float4*)(&z_s[lr * 132 + quad * 8 + (c >> 1) * 32 + (c & 1) * 4]);
    // logits: lg[r] = (z[p] . re[p][r]) / 8   (q.br is softmax-invariant, dropped)
    float lg[10];
#pragma unroll 2
    for (int r = 0; r < 10; ++r) {
      float part = 0.f;
#pragma unroll
      for (int kc = 0; kc < 4; ++kc) {
        bf16x8 rf = *(const bf16x8*)(re_s + lr * 1280 + r * 128 + (((quad + 4 * kc) ^ swz) << 3));
        u32x4 wv = __builtin_bit_cast(u32x4, rf);
#pragma unroll
        for (int m = 0; m < 4; ++m) {
          const float lo = __builtin_bit_cast(float, wv[m] << 16);
          const float hi = __builtin_bit_cast(float, wv[m] & 0xffff0000u);
          part += lo * zr[kc * 2 + (m >> 1)][(m & 1) * 2 + 0];
          part += hi * zr[kc * 2 + (m >> 1)][(m & 1) * 2 + 1];
        }
      }
      part += __shfl_xor(part, 16);
      part += __shfl_xor(part, 32);
      lg[r] = part * 0.125f;
    }
    // softmax over r (per-lane, replicated)
    float mx = lg[0];
#pragma unroll
    for (int r = 1; r < 10; ++r) mx = fmaxf(mx, lg[r]);
    float ssum = 0.f;
#pragma unroll
    for (int r = 0; r < 10; ++r) { lg[r] = __expf(lg[r] - mx); ssum += lg[r]; }
    const float inv = 1.f / ssum;
#pragma unroll
    for (int r = 0; r < 10; ++r) lg[r] *= inv;
    // ws = sum_r a[r] * re[p][r]   (A-layout per lane)
    float ws[4][8] = {};
#pragma unroll 2
    for (int r = 0; r < 10; ++r) {
#pragma unroll
      for (int kc = 0; kc < 4; ++kc) {
        bf16x8 rf = *(const bf16x8*)(re_s + lr * 1280 + r * 128 + (((quad + 4 * kc) ^ swz) << 3));
        u32x4 wv = __builtin_bit_cast(u32x4, rf);
#pragma unroll
        for (int m = 0; m < 4; ++m) {
          const float lo = __builtin_bit_cast(float, wv[m] << 16);
          const float hi = __builtin_bit_cast(float, wv[m] & 0xffff0000u);
          ws[kc][2 * m] += lg[r] * lo;
          ws[kc][2 * m + 1] += lg[r] * hi;
        }
      }
    }
    bf16x8 wf[4];
#pragma unroll
    for (int kc = 0; kc < 4; ++kc)
#pragma unroll
      for (int j = 0; j < 8; ++j) wf[kc][j] = (short)f2bf(ws[kc][j]);
    // out = ws @ Wv^T ; pep_new = q + out + bv  (sum a = 1)
    f32x4 oa[4] = {fz, fz, fz, fz};
#pragma unroll
    for (int kc = 0; kc < 4; ++kc)
#pragma unroll
      for (int n = 0; n < 4; ++n) oa[n] = MFMA(wf[kc], loadBc(WBv, kc * 4 + n, t), oa[n]);
#pragma unroll
    for (int n = 0; n < 4; ++n) {
      const float bvv = bias_s[256 + l * 64 + lr + 16 * n];
#pragma unroll
      for (int i = 0; i < 4; ++i) pcur[n][i] = qa[n][i] + oa[n][i] + bvv;
    }
#pragma unroll
    for (int n = 0; n < 4; ++n)
#pragma unroll
      for (int i = 0; i < 4; ++i)
        bwrite(pep_s, quad * 4 + i, lr + 16 * n, f2bf(pcur[n][i]));
  }

  // ---- pooling head: d = LN(pep); dbuf; logits = W2 tanh(W1 tanh(W0 d)) ----
  {
    float s[4], sq[4];
#pragma unroll
    for (int i = 0; i < 4; ++i) {
      s[i] = pcur[0][i] + pcur[1][i] + pcur[2][i] + pcur[3][i];
      sq[i] = pcur[0][i] * pcur[0][i] + pcur[1][i] * pcur[1][i] +
              pcur[2][i] * pcur[2][i] + pcur[3][i] * pcur[3][i];
    }
#pragma unroll
    for (int msk = 1; msk < 16; msk <<= 1) {
#pragma unroll
      for (int i = 0; i < 4; ++i) {
        s[i] += __shfl_xor(s[i], msk);
        sq[i] += __shfl_xor(sq[i], msk);
      }
    }
    float gv[4], bv2[4];
#pragma unroll
    for (int n = 0; n < 4; ++n) { gv[n] = pool_g[lr + 16 * n]; bv2[n] = pool_b[lr + 16 * n]; }
    f32x4 d[4];
#pragma unroll
    for (int i = 0; i < 4; ++i) {
      const float mean = s[i] * (1.f / 64.f);
      const float var = sq[i] * (1.f / 64.f) - mean * mean;
      const float rstd = rsqrtf(var + 1e-5f);
#pragma unroll
      for (int n = 0; n < 4; ++n) d[n][i] = (pcur[n][i] - mean) * rstd * gv[n] + bv2[n];
    }
    // dbuf (fp32) via LDS transpose -> coalesced store
#pragma unroll
    for (int n = 0; n < 4; ++n)
#pragma unroll
      for (int i = 0; i < 4; ++i)
        stg_s[(quad * 4 + i) * 64 + lr + 16 * n] = d[n][i];
#pragma unroll
    for (int i = 0; i < 4; ++i) {
      const float4 v = *(const float4*)(&stg_s[i * 256 + t * 4]);
      *(float4*)(dbuf + (size_t)pbase * 64 + i * 256 + t * 4) = v;
    }
    // d -> bf16 frags
#pragma unroll
    for (int n = 0; n < 4; ++n)
#pragma unroll
      for (int i = 0; i < 4; ++i)
        bwrite(q_s, quad * 4 + i, lr + 16 * n, f2bf(d[n][i]));
    const bf16x8 ad0 = bfrag(q_s, 0), ad1 = bfrag(q_s, 1);
    f32x4 h0[4] = {fz, fz, fz, fz};
#pragma unroll
    for (int n = 0; n < 4; ++n) {
      h0[n] = MFMA(ad0, loadBc(WB + WB_W0_OFF, n, t), h0[n]);
      h0[n] = MFMA(ad1, loadBc(WB + WB_W0_OFF, 4 + n, t), h0[n]);
    }
#pragma unroll
    for (int n = 0; n < 4; ++n)
#pragma unroll
      for (int i = 0; i < 4; ++i)
        bwrite(q_s, quad * 4 + i, lr + 16 * n, f2bf(tanhf_fast(h0[n][i])));
    const bf16x8 ah00 = bfrag(q_s, 0), ah01 = bfrag(q_s, 1);
    f32x4 h1[2] = {fz, fz};
#pragma unroll
    for (int n = 0; n < 2; ++n) {
      h1[n] = MFMA(ah00, loadBc(WB + WB_W1_OFF, n, t), h1[n]);
      h1[n] = MFMA(ah01, loadBc(WB + WB_W1_OFF, 2 + n, t), h1[n]);
    }
#pragma unroll
    for (int n = 0; n < 2; ++n)
#pragma unroll
      for (int i = 0; i < 4; ++i)
        bwrite(q_s, quad * 4 + i, lr + 16 * n, f2bf(tanhf_fast(h1[n][i])));
    const bf16x8 ah1 = bfrag(q_s, 0);
    f32x4 lac = MFMA(ah1, loadBc(WB + WB_W2_OFF, 0, t), fz);
    // logitsT[(b*16+h)*2048 + s]
    const int b = pbase >> 11, sx0 = pbase & 2047;
#pragma unroll
    for (int i = 0; i < 4; ++i)
      logitsT[(size_t)(b * 16 + lr) * 2048 + sx0 + quad * 4 + i] = lac[i];
  }
}

// ---------------- double softmax over s + attended ----------------
__global__ __launch_bounds__(256) void k_pool2(
    const float* __restrict__ logitsT, const float* __restrict__ dbuf,
    float* __restrict__ attended) {
  __shared__ float sh[2048];
  __shared__ float red[8];
  __shared__ float accs[4][64];
  const int bh = blockIdx.x, b = bh >> 4;
  const int tid = threadIdx.x, lane = tid & 63, wid = tid >> 6;
  const float* lrow = logitsT + (size_t)bh * 2048;

  float m = -1e30f;
  for (int sx = tid; sx < 2048; sx += 256) {
    float v = lrow[sx];
    sh[sx] = v;
    m = fmaxf(m, v);
  }
#pragma unroll
  for (int msk = 1; msk < 64; msk <<= 1) m = fmaxf(m, __shfl_xor(m, msk));
  if (lane == 0) red[wid] = m;
  __syncthreads();
  m = fmaxf(fmaxf(red[0], red[1]), fmaxf(red[2], red[3]));

  float s1 = 0.f;
  for (int sx = tid; sx < 2048; sx += 256) {
    float e = __expf(sh[sx] - m);
    sh[sx] = e;
    s1 += e;
  }
#pragma unroll
  for (int msk = 1; msk < 64; msk <<= 1) s1 += __shfl_xor(s1, msk);
  __syncthreads();
  if (lane == 0) red[4 + wid] = s1;
  __syncthreads();
  s1 = red[4] + red[5] + red[6] + red[7];
  const float invS1 = 1.f / s1;

  float s2 = 0.f;
  for (int sx = tid; sx < 2048; sx += 256) {
    float e2 = __expf((sh[sx] - 1.f) * invS1);
    sh[sx] = e2;
    s2 += e2;
  }
#pragma unroll
  for (int msk = 1; msk < 64; msk <<= 1) s2 += __shfl_xor(s2, msk);
  __syncthreads();
  if (lane == 0) red[wid] = s2;
  __syncthreads();
  s2 = red[0] + red[1] + red[2] + red[3];
  const float invS2 = 1.f / s2;

  float acc = 0.f;
  for (int sx = wid; sx < 2048; sx += 4)
    acc += sh[sx] * dbuf[((size_t)b * 2048 + sx) * 64 + lane];
  accs[wid][lane] = acc * invS2;
  __syncthreads();
  if (tid < 64)
    attended[(size_t)bh * 64 + tid] =
        accs[0][tid] + accs[1][tid] + accs[2][tid] + accs[3][tid];
}

// ---------------- pooled mean over heads + final projection ----------------
__global__ __launch_bounds__(256) void k_final(
    const float* __restrict__ attended, const float* __restrict__ W,
    const float* __restrict__ bias, float* __restrict__ out) {
  __shared__ float pooled[4][64];
  const int tid = threadIdx.x;
  {
    const int b = tid >> 6, d = tid & 63;
    float s = 0.f;
#pragma unroll
    for (int h = 0; h < 16; ++h) s += attended[((size_t)b * 16 + h) * 64 + d];
    pooled[b][d] = s * (1.f / 16.f);
  }
  __syncthreads();
  if (tid < 128) {
    const int b = tid >> 5, j = tid & 31;
    float s = bias[j];
#pragma unroll
    for (int d2 = 0; d2 < 64; ++d2) s += pooled[b][d2] * W[j * 64 + d2];
    out[b * 32 + j] = s;
  }
}

extern "C" void kernel_launch(void* const* d_in, const int* in_sizes, int n_in,
                              void* d_out, int out_size, void* d_ws, size_t ws_size,
                              hipStream_t stream) {
  const float* pep_feat = (const float*)d_in[0];
  const float* rec_feat = (const float*)d_in[1];
  const float* edge_feat = (const float*)d_in[2];
  const float* W_rec_esm = (const float*)d_in[3];
  const float* W_pep_esm = (const float*)d_in[4];
  const float* W_pep_emb = (const float*)d_in[5];
  const float* W_rec_emb = (const float*)d_in[6];
  const float* W_edge_emb = (const float*)d_in[7];
  const float* pep_ln_g = (const float*)d_in[8];
  const float* pep_ln_b = (const float*)d_in[9];
  const float* rec_ln_g = (const float*)d_in[10];
  const float* rec_ln_b = (const float*)d_in[11];
  const float* ga_Wp = (const float*)d_in[12];
  const float* ga_bp = (const float*)d_in[13];
  const float* ga_Wr = (const float*)d_in[14];
  const float* ga_br = (const float*)d_in[15];
  const float* ga_Wv = (const float*)d_in[16];
  const float* ga_bv = (const float*)d_in[17];
  const float* pool_ln_g = (const float*)d_in[18];
  const float* pool_ln_b = (const float*)d_in[19];
  const float* pool_W0 = (const float*)d_in[20];
  const float* pool_W1 = (const float*)d_in[21];
  const float* pool_W2 = (const float*)d_in[22];
  const float* mlp_W = (const float*)d_in[23];
  const float* mlp_b = (const float*)d_in[24];
  float* out = (float*)d_out;
  (void)ga_br;  // softmax-invariant, algebraically dropped
  (void)ws_size; (void)in_sizes; (void)n_in; (void)out_size;

  char* ws = (char*)d_ws;
  unsigned short* WB = (unsigned short*)(ws);                 // 517120 B (pad->524288)
  unsigned short* rec_edge = (unsigned short*)(ws + 524288);  // 20971520 B
  float* dbuf = (float*)(ws + 21495808);                      // 2097152 B
  float* logitsT = (float*)(ws + 23592960);                   // 524288 B
  float* attended = (float*)(ws + 24117248);                  // 16384 B

  k_pack<<<1010, 256, 0, stream>>>(W_rec_esm, W_pep_esm, W_rec_emb, W_pep_emb,
                                   W_edge_emb, ga_Wp, ga_Wr, ga_Wv,
                                   pool_W0, pool_W1, pool_W2, WB);
  k_rec<<<1280, 256, 0, stream>>>(rec_feat, edge_feat, WB, rec_ln_g, rec_ln_b,
                                  rec_edge);
  k_fused<<<512, 64, 0, stream>>>(pep_feat, rec_edge, WB, ga_bp, ga_bv,
                                  pep_ln_g, pep_ln_b, pool_ln_g, pool_ln_b,
                                  dbuf, logitsT);
  k_pool2<<<64, 256, 0, stream>>>(logitsT, dbuf, attended);
  k_final<<<1, 256, 0, stream>>>(attended, mlp_W, mlp_b, out);
}